// Round 2
// baseline (149.790 us; speedup 1.0000x reference)
//
#include <hip/hip_runtime.h>

// x volumes: [256,256,256] fp32. Row (d,h) = 256 floats = 64 float4.
// float4-unit offset: d*16384 + h*64 + lane.
//
// R8: barrier-free restructure. R7's fence-free barrier was NEUTRAL (48->46us)
// and L3-resident replays run at the same speed as cold runs => the ~45us
// floor shared by three different structures is the block-wide lockstep
// cadence (all waves sync on the same load->stage->compute chain every d-step,
// ~1500cy of loaded L2/L3 latency exposed per step), not BW, not VMEM count.
// Fix: no LDS, no barriers. Each wave loads rows r-1,r,r+1 itself (contiguous
// 1KB float4 loads only -- the R4-R6 no-LDS failure was the 4 sparse
// 16B-stride edge loads, which __shfl already replaced). Registers roll the
// d-axis for all 3 rows; waves free-run with loads 1+ step ahead.
// Intra-block 2x row redundancy -> L1; cross-tile redundancy kept on-XCD by
// a contiguous swizzle (adjacent htiles / dchunks share an XCD L2).
// R3 lesson: no __threadfence / fused finalize (per-XCD L2 writeback storm).
//
// Grid: 64 htiles x 16 d-chunks (16 deep) = 1024 blocks x 256 thr (= 4/CU),
// ~100 VGPR, no loop LDS.

#define D_CHUNK 16

__global__ __launch_bounds__(256, 4) void grad_loss_kernel(const float* __restrict__ xf1,
                                                           const float* __restrict__ xf2,
                                                           double* __restrict__ acc) {
    const float4* __restrict__ x1 = (const float4*)xf1;
    const float4* __restrict__ x2 = (const float4*)xf2;

    const int tid  = threadIdx.x;
    const int lane = tid & 63;
    const int wid  = tid >> 6;          // 0..3

    // XCD-contiguous swizzle: 1024 blocks, 8 XCDs round-robin on raw
    // blockIdx. Remap so XCD k owns 128 consecutive work-ids = full h-range
    // of 2 adjacent d-chunks -> h-edge and d-edge overlap stays in one L2.
    const int orig = blockIdx.x;
    const int wg   = (orig & 7) * 128 + (orig >> 3);
    const int htile = wg & 63;          // 0..63
    const int dchk  = wg >> 6;          // 0..15

    const int  r    = 1 + htile * 4 + wid;          // 1..256
    const bool live = (r <= 254);
    const int  rc   = (r <= 255) ? r : 255;         // clamped own row
    const int  rm   = r - 1;                        // 0..255, always valid
    const int  rp   = (r + 1 <= 255) ? (r + 1) : 255;

    const int iU = rm * 64 + lane;      // row r-1
    const int iC = rc * 64 + lane;      // row r
    const int iV = rp * 64 + lane;      // row r+1

    const int d0 = 1 + dchk * D_CHUNK;  // computed depths d0..d0+15 (tail >254 dead)

    // per-voxel w-axis weights (0 = excluded border, 2 = edge-replicated)
    const float ww0 = (lane == 0)  ? 0.0f : 1.0f;   // w = 4*lane   (w==0)
    const float ww1 = (lane == 0)  ? 2.0f : 1.0f;   // w = 4*lane+1 (w==1)
    const float ww2 = (lane == 63) ? 2.0f : 1.0f;   // w = 4*lane+2 (w==254)
    const float ww3 = (lane == 63) ? 0.0f : 1.0f;   // w = 4*lane+3 (w==255)
    const float whf = (r == 1 || r == 254) ? 2.0f : 1.0f;

    // ---- prologue: plane d0-1 own row; planes d0, d0+1 all 3 rows.
    float4 a1  = x1[(d0 - 1) * 16384 + iC];
    float4 a2  = x2[(d0 - 1) * 16384 + iC];
    float4 bU1 = x1[d0 * 16384 + iU];
    float4 bC1 = x1[d0 * 16384 + iC];
    float4 bV1 = x1[d0 * 16384 + iV];
    float4 bU2 = x2[d0 * 16384 + iU];
    float4 bC2 = x2[d0 * 16384 + iC];
    float4 bV2 = x2[d0 * 16384 + iV];
    float4 cU1 = x1[(d0 + 1) * 16384 + iU];   // d0+1 <= 242 always
    float4 cC1 = x1[(d0 + 1) * 16384 + iC];
    float4 cV1 = x1[(d0 + 1) * 16384 + iV];
    float4 cU2 = x2[(d0 + 1) * 16384 + iU];
    float4 cC2 = x2[(d0 + 1) * 16384 + iC];
    float4 cV2 = x2[(d0 + 1) * 16384 + iV];

    float val = 0.0f;

    #pragma unroll 2
    for (int i = 0; i < D_CHUNK; ++i) {
        const int d  = d0 + i;
        const int dn = (d + 2 <= 255) ? (d + 2) : 255;   // prefetch depth (clamped tail)
        const int off = dn * 16384;

        // prefetch plane d+2, rows r-1/r/r+1, both inputs (consumed next step)
        float4 qU1 = x1[off + iU];
        float4 qC1 = x1[off + iC];
        float4 qV1 = x1[off + iV];
        float4 qU2 = x2[off + iU];
        float4 qC2 = x2[off + iC];
        float4 qV2 = x2[off + iV];

        if (live && d <= 254) {
            float l1 = __shfl_up(bC1.w, 1, 64);          // lane0: self -> finite, ww0=0
            float r1 = __shfl_down(bC1.x, 1, 64);        // lane63: self -> finite, ww3=0
            float l2 = __shfl_up(bC2.w, 1, 64);
            float r2 = __shfl_down(bC2.x, 1, 64);

            float gw, gd, gh;
            gw = cC1.x - a1.x; gd = bV1.x - bU1.x; gh = bC1.y - l1;
            float m10 = __builtin_amdgcn_sqrtf(gw * gw + gd * gd + gh * gh + 1e-6f);
            gw = cC1.y - a1.y; gd = bV1.y - bU1.y; gh = bC1.z - bC1.x;
            float m11 = __builtin_amdgcn_sqrtf(gw * gw + gd * gd + gh * gh + 1e-6f);
            gw = cC1.z - a1.z; gd = bV1.z - bU1.z; gh = bC1.w - bC1.y;
            float m12 = __builtin_amdgcn_sqrtf(gw * gw + gd * gd + gh * gh + 1e-6f);
            gw = cC1.w - a1.w; gd = bV1.w - bU1.w; gh = r1 - bC1.z;
            float m13 = __builtin_amdgcn_sqrtf(gw * gw + gd * gd + gh * gh + 1e-6f);

            gw = cC2.x - a2.x; gd = bV2.x - bU2.x; gh = bC2.y - l2;
            float m20 = __builtin_amdgcn_sqrtf(gw * gw + gd * gd + gh * gh + 1e-6f);
            gw = cC2.y - a2.y; gd = bV2.y - bU2.y; gh = bC2.z - bC2.x;
            float m21 = __builtin_amdgcn_sqrtf(gw * gw + gd * gd + gh * gh + 1e-6f);
            gw = cC2.z - a2.z; gd = bV2.z - bU2.z; gh = bC2.w - bC2.y;
            float m22 = __builtin_amdgcn_sqrtf(gw * gw + gd * gd + gh * gh + 1e-6f);
            gw = cC2.w - a2.w; gd = bV2.w - bU2.w; gh = r2 - bC2.z;
            float m23 = __builtin_amdgcn_sqrtf(gw * gw + gd * gd + gh * gh + 1e-6f);

            float inner = ww0 * fabsf(m10 - m20)
                        + ww1 * fabsf(m11 - m21)
                        + ww2 * fabsf(m12 - m22)
                        + ww3 * fabsf(m13 - m23);

            const float wdf = (d == 1 || d == 254) ? 2.0f : 1.0f;
            val += wdf * whf * inner;
        }

        // roll the depth pipeline (renames after unroll; vmcnt waits are
        // counted, landing before next step's first use of the q regs)
        a1 = bC1; bU1 = cU1; bC1 = cC1; bV1 = cV1; cU1 = qU1; cC1 = qC1; cV1 = qV1;
        a2 = bC2; bU2 = cU2; bC2 = cC2; bV2 = cV2; cU2 = qU2; cC2 = qC2; cV2 = qV2;
    }

    // wave-64 reduction
    for (int off = 32; off > 0; off >>= 1)
        val += __shfl_down(val, off, 64);

    __shared__ float smem[4];
    if (lane == 0) smem[wid] = val;
    __syncthreads();

    if (wid == 0) {
        float s = (lane < 4) ? smem[lane] : 0.0f;
        s += __shfl_down(s, 2, 64);
        s += __shfl_down(s, 1, 64);
        if (lane == 0)
            atomicAdd(&acc[blockIdx.x & 255], (double)s);   // no fence!
    }
}

__global__ void finalize_kernel(const double* __restrict__ acc, float* __restrict__ out) {
    double v = acc[threadIdx.x];   // 256 threads, one slot each
    for (int off = 32; off > 0; off >>= 1)
        v += __shfl_down(v, off, 64);

    __shared__ double smem[4];
    const int lid = threadIdx.x & 63;
    const int wid = threadIdx.x >> 6;
    if (lid == 0) smem[wid] = v;
    __syncthreads();

    if (threadIdx.x == 0) {
        double s = smem[0] + smem[1] + smem[2] + smem[3];
        out[0] = (float)(s / 16777216.0);   // mean over 256^3
    }
}

extern "C" void kernel_launch(void* const* d_in, const int* in_sizes, int n_in,
                              void* d_out, int out_size, void* d_ws, size_t ws_size,
                              hipStream_t stream) {
    const float* x1 = (const float*)d_in[0];
    const float* x2 = (const float*)d_in[1];
    float* out = (float*)d_out;
    double* acc = (double*)d_ws;   // 256 doubles = 2 KiB scratch

    hipMemsetAsync(d_ws, 0, 256 * sizeof(double), stream);
    grad_loss_kernel<<<64 * 16, 256, 0, stream>>>(x1, x2, acc);
    finalize_kernel<<<1, 256, 0, stream>>>(acc, out);
}